// Round 8
// baseline (332.699 us; speedup 1.0000x reference)
//
#include <hip/hip_runtime.h>

#define N_NODES 50000
#define N_EDGES 1600000
#define IN_F 256
#define H1_F 128
#define H2_F 64
#define OUT_F 2
#define BN_EPS 1e-5f

#define NBUK 782          // ceil(50000/64) buckets of 64 nodes
#define BCAP 3584         // LDS edge capacity per bucket in build (avg 2048)
#define CHUNK 8192        // edges per chunk in the two-level counting sort
#define NCHUNK 196        // ceil(1600000/8192)
#define FC 32             // features per aggregation chunk (slice = N*32*2B = 3.2MB < 4MiB L2)

typedef __attribute__((ext_vector_type(8))) short bf16x8;   // 8 bf16 in 4 VGPRs
typedef __attribute__((ext_vector_type(4))) float f32x4;
typedef __attribute__((ext_vector_type(4))) int   i32x4;    // ext-vector (nontemporal-compatible)

// ---------------------------------------------------------------- bf16 helpers
__device__ __forceinline__ unsigned short f2b(float f) {
    union { float f; unsigned u; } v; v.f = f;
    unsigned r = (v.u + 0x7FFFu + ((v.u >> 16) & 1u)) >> 16;
    return (unsigned short)r;
}
__device__ __forceinline__ float b2f(unsigned short b) {
    union { unsigned u; float f; } v; v.u = ((unsigned)b) << 16;
    return v.f;
}
__device__ __forceinline__ void add2(float& a0, float& a1, unsigned u) {
    union { unsigned u; float f; } lo, hi;
    lo.u = u << 16;
    hi.u = u & 0xFFFF0000u;
    a0 += lo.f; a1 += hi.f;
}

// ---------------------------------------------------------------- pass A: per-chunk bucket histogram
__launch_bounds__(512)
__global__ void chist_kernel(const int* __restrict__ dst, int* __restrict__ h) {
    __shared__ int lh[NBUK];
    const int c = blockIdx.x;
    for (int i = threadIdx.x; i < NBUK; i += 512) lh[i] = 0;
    __syncthreads();
    const int e0 = c * CHUNK;
    const int e1 = min(e0 + CHUNK, N_EDGES);
    const i32x4* p = (const i32x4*)(dst + e0);
    const int n4 = (e1 - e0) >> 2;
    for (int i = threadIdx.x; i < n4; i += 512) {
        i32x4 d = __builtin_nontemporal_load(p + i);
        atomicAdd(&lh[d.x >> 6], 1);
        atomicAdd(&lh[d.y >> 6], 1);
        atomicAdd(&lh[d.z >> 6], 1);
        atomicAdd(&lh[d.w >> 6], 1);
    }
    __syncthreads();
    for (int i = threadIdx.x; i < NBUK; i += 512)
        h[c * NBUK + i] = lh[i];
}

// ---------------------------------------------------------------- pass B: totals -> scan -> per-(chunk,bucket) offsets
__global__ void bscan2_kernel(int* __restrict__ h, int* __restrict__ boff,
                              int* __restrict__ rowptr) {
    __shared__ int tmp[1024];
    const int t = threadIdx.x;
    int tot = 0;
    if (t < NBUK)
        for (int c = 0; c < NCHUNK; ++c) tot += h[c * NBUK + t];
    tmp[t] = tot;
    __syncthreads();
    for (int off = 1; off < 1024; off <<= 1) {
        int a = (t >= off) ? tmp[t - off] : 0;
        __syncthreads();
        tmp[t] += a;
        __syncthreads();
    }
    const int excl = tmp[t] - tot;
    if (t < NBUK) boff[t] = excl;
    if (t == 0) { boff[NBUK] = N_EDGES; rowptr[N_NODES] = N_EDGES; }
    if (t < NBUK) {
        int run = excl;
        for (int c = 0; c < NCHUNK; ++c) {
            int v = h[c * NBUK + t];
            h[c * NBUK + t] = run;
            run += v;
        }
    }
}

// ---------------------------------------------------------------- pass C: scatter to precomputed slots (LDS cursors only)
__launch_bounds__(512)
__global__ void cscatter_kernel(const int* __restrict__ src, const int* __restrict__ dst,
                                const int* __restrict__ h, unsigned* __restrict__ bedges) {
    __shared__ int cur[NBUK];
    const int c = blockIdx.x;
    for (int i = threadIdx.x; i < NBUK; i += 512) cur[i] = h[c * NBUK + i];
    __syncthreads();
    const int e0 = c * CHUNK;
    const int e1 = min(e0 + CHUNK, N_EDGES);
    const i32x4* pd = (const i32x4*)(dst + e0);
    const i32x4* ps = (const i32x4*)(src + e0);
    const int n4 = (e1 - e0) >> 2;
    for (int i = threadIdx.x; i < n4; i += 512) {
        i32x4 d = __builtin_nontemporal_load(pd + i);
        i32x4 s = __builtin_nontemporal_load(ps + i);
        int slot;
        slot = atomicAdd(&cur[d.x >> 6], 1); bedges[slot] = (unsigned)s.x | ((unsigned)d.x << 16);
        slot = atomicAdd(&cur[d.y >> 6], 1); bedges[slot] = (unsigned)s.y | ((unsigned)d.y << 16);
        slot = atomicAdd(&cur[d.z >> 6], 1); bedges[slot] = (unsigned)s.z | ((unsigned)d.z << 16);
        slot = atomicAdd(&cur[d.w >> 6], 1); bedges[slot] = (unsigned)s.w | ((unsigned)d.w << 16);
    }
}

// ---------------------------------------------------------------- per-bucket CSR build
__launch_bounds__(256)
__global__ void build_kernel(const unsigned* __restrict__ bedges, const int* __restrict__ boff,
                             unsigned short* __restrict__ perm, int* __restrict__ rowptr,
                             float* __restrict__ dinv) {
    __shared__ unsigned e_lds[BCAP];
    __shared__ unsigned short p_lds[BCAP];
    __shared__ int ncnt[64], ncur[64];

    const int b = blockIdx.x;
    const int t = threadIdx.x;
    const int start = boff[b];
    const int end   = boff[b + 1];
    const int cnt   = end - start;
    const bool fits = (cnt <= BCAP);

    if (t < 64) ncnt[t] = 0;
    __syncthreads();

    for (int i = t; i < cnt; i += 256) {
        unsigned e = bedges[start + i];
        if (fits) e_lds[i] = e;
        atomicAdd(&ncnt[(e >> 16) & 63], 1);
    }
    __syncthreads();

    if (t == 0) {
        int a = 0;
        for (int i = 0; i < 64; ++i) { ncur[i] = a; a += ncnt[i]; }
    }
    __syncthreads();

    if (t < 64) {
        int node = b * 64 + t;
        if (node < N_NODES) {
            rowptr[node] = start + ncur[t];
            dinv[node]   = rsqrtf((float)ncnt[t] + 1.0f);   // +1 self loop
        }
    }
    __syncthreads();

    for (int i = t; i < cnt; i += 256) {
        unsigned e = fits ? e_lds[i] : bedges[start + i];
        int slot = atomicAdd(&ncur[(e >> 16) & 63], 1);
        unsigned short s = (unsigned short)(e & 0xFFFFu);
        if (fits) p_lds[slot] = s;
        else      perm[start + slot] = s;
    }
    if (fits) {
        __syncthreads();
        for (int i = t; i < cnt; i += 256) perm[start + i] = p_lds[i];
    }
}

// ---------------------------------------------------------------- weight transpose+convert: WT[n][k] = bf16(W[k][n])
__global__ void wt_kernel(const float* __restrict__ W, unsigned short* __restrict__ WT,
                          int K, int N) {
    int i = blockIdx.x * blockDim.x + threadIdx.x;
    if (i < N * K) {
        int n = i / K, k = i % K;
        WT[i] = f2b(W[(size_t)k * N + n]);
    }
}

// ---------------------------------------------------------------- MFMA GEMM, chunk-major bf16 output
// C layout: [f>>5][r][f&31] (chunk-major, FC=32).  A: row-major fp32, or chunk-major bf16.
template <int KSTEPS, int NTILES, bool A_BF16_CHUNKED>
__launch_bounds__(256)
__global__ void mfma_gemm_kernel(const void* __restrict__ Ap, const unsigned short* __restrict__ BT,
                                 const float* __restrict__ dscale, unsigned short* __restrict__ C,
                                 int M) {
    constexpr int K  = KSTEPS * 32;
    const int wave = threadIdx.x >> 6;
    const int lane = threadIdx.x & 63;
    const int r0   = (blockIdx.x * 4 + wave) * 16;
    const int m    = lane & 15;
    const int kb   = lane >> 4;          // 0..3

    int arow = r0 + m;
    if (arow >= M) arow = M - 1;         // clamp loads; stores guarded

    f32x4 acc[NTILES];
#pragma unroll
    for (int nt = 0; nt < NTILES; ++nt) acc[nt] = (f32x4)(0.f);

#pragma unroll
    for (int ks = 0; ks < KSTEPS; ++ks) {
        const int k0 = ks * 32 + kb * 8;
        bf16x8 a;
        if constexpr (A_BF16_CHUNKED) {
            // chunk-major bf16: [ks][row][32]; kb*8 never crosses the 32-boundary
            a = *(const bf16x8*)((const unsigned short*)Ap +
                                 (size_t)ks * N_NODES * FC + (size_t)arow * FC + kb * 8);
        } else {
            const float* af = (const float*)Ap + (size_t)arow * K + k0;
            f32x4 lo = __builtin_nontemporal_load((const f32x4*)af);
            f32x4 hi = __builtin_nontemporal_load((const f32x4*)(af + 4));
            union { bf16x8 v; unsigned short u[8]; } pk;
            pk.u[0] = f2b(lo.x); pk.u[1] = f2b(lo.y); pk.u[2] = f2b(lo.z); pk.u[3] = f2b(lo.w);
            pk.u[4] = f2b(hi.x); pk.u[5] = f2b(hi.y); pk.u[6] = f2b(hi.z); pk.u[7] = f2b(hi.w);
            a = pk.v;
        }
#pragma unroll
        for (int nt = 0; nt < NTILES; ++nt) {
            bf16x8 b = *(const bf16x8*)(BT + (size_t)(nt * 16 + m) * K + k0);
            acc[nt] = __builtin_amdgcn_mfma_f32_16x16x32_bf16(a, b, acc[nt], 0, 0, 0);
        }
    }

#pragma unroll
    for (int reg = 0; reg < 4; ++reg) {
        const int r = r0 + kb * 4 + reg;
        if (r < M) {
            const float ds = dscale[r];
#pragma unroll
            for (int nt = 0; nt < NTILES; ++nt) {
                // feature f = nt*16 + m -> chunk nt>>1, within-chunk (nt&1)*16 + m
                C[(size_t)(nt >> 1) * N_NODES * FC + (size_t)r * FC + ((nt & 1) << 4) + m] =
                    f2b(acc[nt][reg] * ds);
            }
        }
    }
}

// ---------------------------------------------------------------- chunked aggregation (one 3.2MB slice per pass)
//   blockIdx.y = feature chunk c; wave per node; 4 edge-groups x 16 lanes x 4B loads
__launch_bounds__(256)
__global__ void agg_kernel(const int* __restrict__ rowptr, const unsigned short* __restrict__ perm,
                           const unsigned short* __restrict__ xw,   // chunk-major [c][node][FC]
                           const float* __restrict__ dinv,
                           const float* __restrict__ bias, const float* __restrict__ g,
                           const float* __restrict__ be, const float* __restrict__ m,
                           const float* __restrict__ v,
                           unsigned short* __restrict__ out) {     // chunk-major [c][node][FC]
    const int c = blockIdx.y;
    const unsigned short* xc = xw + (size_t)c * N_NODES * FC;
    const int wave = threadIdx.x >> 6;
    const int node = blockIdx.x * 4 + wave;
    if (node >= N_NODES) return;
    const int lane = threadIdx.x & 63;
    const int grp  = lane >> 4;          // 4 edge groups
    const int fp   = (lane & 15) << 1;   // 2 feats per lane within chunk

    float a0 = 0.f, a1 = 0.f;
    if (grp == 0) {
        unsigned u = *(const unsigned*)(xc + node * FC + fp);
        add2(a0, a1, u);                 // self term
    }

    const int start = rowptr[node];
    const int end   = rowptr[node + 1];
    for (int base = start; base < end; base += 64) {
        int pidx = base + lane;
        int pv = (int)__builtin_nontemporal_load(perm + (pidx < end ? pidx : end - 1));
        int ne = end - base;
        if (ne > 64) ne = 64;
        if (ne == 64) {
#pragma unroll
            for (int j = 0; j < 64; j += 4) {
                int s = __shfl(pv, j + grp);
                unsigned u = *(const unsigned*)(xc + s * FC + fp);
                add2(a0, a1, u);
            }
        } else {
            for (int j = 0; j < ne; j += 4) {
                int s = __shfl(pv, j + grp);
                if (j + grp < ne) {
                    unsigned u = *(const unsigned*)(xc + s * FC + fp);
                    add2(a0, a1, u);
                }
            }
        }
    }

    // combine the 4 edge-groups
    a0 += __shfl_xor(a0, 16); a1 += __shfl_xor(a1, 16);
    a0 += __shfl_xor(a0, 32); a1 += __shfl_xor(a1, 32);

    if (lane < 16) {
        const float dv = dinv[node];
        const int f = c * FC + fp;
        float s0  = g[f] * rsqrtf(v[f] + BN_EPS);
        float s1  = g[f + 1] * rsqrtf(v[f + 1] + BN_EPS);
        float sh0 = (bias[f] - m[f]) * s0 + be[f];
        float sh1 = (bias[f + 1] - m[f + 1]) * s1 + be[f + 1];
        float y0 = fmaxf(a0 * dv * s0 + sh0, 0.f);
        float y1 = fmaxf(a1 * dv * s1 + sh1, 0.f);
        unsigned o = (unsigned)f2b(y0) | ((unsigned)f2b(y1) << 16);
        __builtin_nontemporal_store(o, (unsigned*)(out + (size_t)c * N_NODES * FC + node * FC + fp));
    }
}

// ---------------------------------------------------------------- final linear 64 -> 2 (reads chunk-major bf16 h2)
__global__ void final_kernel(const unsigned short* __restrict__ h2, const float* __restrict__ Wl,
                             const float* __restrict__ bl, float* __restrict__ out) {
    __shared__ float w[H2_F * OUT_F];
    if (threadIdx.x < H2_F * OUT_F) w[threadIdx.x] = Wl[threadIdx.x];
    __syncthreads();
    const int i = blockIdx.x * blockDim.x + threadIdx.x;
    if (i >= N_NODES) return;
    float p0 = bl[0], p1 = bl[1];
#pragma unroll
    for (int cc = 0; cc < 2; ++cc) {
        const unsigned* p = (const unsigned*)(h2 + (size_t)cc * N_NODES * FC + i * FC);
#pragma unroll
        for (int q = 0; q < 16; ++q) {
            unsigned t = p[q];
            int f = cc * FC + q * 2;
            float y0 = b2f((unsigned short)(t & 0xFFFF));
            float y1 = b2f((unsigned short)(t >> 16));
            p0 += y0 * w[f * 2 + 0] + y1 * w[(f + 1) * 2 + 0];
            p1 += y0 * w[f * 2 + 1] + y1 * w[(f + 1) * 2 + 1];
        }
    }
    out[(size_t)i * 2 + 0] = p0;
    out[(size_t)i * 2 + 1] = p1;
}

// ---------------------------------------------------------------- launcher
extern "C" void kernel_launch(void* const* d_in, const int* in_sizes, int n_in,
                              void* d_out, int out_size, void* d_ws, size_t ws_size,
                              hipStream_t stream) {
    const float* x   = (const float*)d_in[0];
    const int*   ei  = (const int*)d_in[1];
    const float* W1  = (const float*)d_in[2];
    const float* b1  = (const float*)d_in[3];
    const float* g1  = (const float*)d_in[4];
    const float* be1 = (const float*)d_in[5];
    const float* m1  = (const float*)d_in[6];
    const float* v1  = (const float*)d_in[7];
    const float* W2  = (const float*)d_in[8];
    const float* b2  = (const float*)d_in[9];
    const float* g2  = (const float*)d_in[10];
    const float* be2 = (const float*)d_in[11];
    const float* m2  = (const float*)d_in[12];
    const float* v2  = (const float*)d_in[13];
    const float* Wl  = (const float*)d_in[14];
    const float* bl  = (const float*)d_in[15];

    const int* src = ei;            // edge_index[0]
    const int* dst = ei + N_EDGES;  // edge_index[1]

    // workspace layout (4B units; all chunks 16B-aligned)
    int*            h      = (int*)d_ws;                          // NCHUNK*NBUK
    int*            boff   = h + NCHUNK * NBUK;                   // 1024
    int*            rowptr = boff + 1024;                         // 50016
    float*          dinv   = (float*)(rowptr + 50016);            // 50016
    unsigned*       bedges = (unsigned*)(dinv + 50016);           // E
    unsigned short* perm   = (unsigned short*)(bedges + N_EDGES); // E ushorts
    unsigned short* xwb    = perm + N_EDGES;                      // N*128 bf16 (chunk-major)
    unsigned short* h1b    = xwb + (size_t)N_NODES * H1_F;        // N*128 bf16 (chunk-major)
    unsigned short* w1t    = h1b + (size_t)N_NODES * H1_F;        // 128*256 bf16
    unsigned short* w2t    = w1t + H1_F * IN_F;                   // 64*128 bf16

    // ---- CSR build (deterministic slots, no global returning atomics) ----
    chist_kernel<<<NCHUNK, 512, 0, stream>>>(dst, h);
    bscan2_kernel<<<1, 1024, 0, stream>>>(h, boff, rowptr);
    cscatter_kernel<<<NCHUNK, 512, 0, stream>>>(src, dst, h, bedges);
    build_kernel<<<NBUK, 256, 0, stream>>>(bedges, boff, perm, rowptr, dinv);

    // ---- weight transpose/convert ----
    wt_kernel<<<(H1_F * IN_F + 255) / 256, 256, 0, stream>>>(W1, w1t, IN_F, H1_F);
    wt_kernel<<<(H2_F * H1_F + 255) / 256, 256, 0, stream>>>(W2, w2t, H1_F, H2_F);

    // ---- layer 1 ----
    mfma_gemm_kernel<IN_F / 32, H1_F / 16, false><<<(N_NODES + 63) / 64, 256, 0, stream>>>(
        x, w1t, dinv, xwb, N_NODES);
    agg_kernel<<<dim3((N_NODES + 3) / 4, H1_F / FC), 256, 0, stream>>>(
        rowptr, perm, xwb, dinv, b1, g1, be1, m1, v1, h1b);

    // ---- layer 2 ----
    mfma_gemm_kernel<H1_F / 32, H2_F / 16, true><<<(N_NODES + 63) / 64, 256, 0, stream>>>(
        h1b, w2t, dinv, xwb, N_NODES);
    agg_kernel<<<dim3((N_NODES + 3) / 4, H2_F / FC), 256, 0, stream>>>(
        rowptr, perm, xwb, dinv, b2, g2, be2, m2, v2, h1b);

    // ---- final linear ----
    final_kernel<<<(N_NODES + 255) / 256, 256, 0, stream>>>(h1b, Wl, bl, (float*)d_out);
}

// Round 9
// 321.658 us; speedup vs baseline: 1.0343x; 1.0343x over previous
//
#include <hip/hip_runtime.h>

#define N_NODES 50000
#define N_EDGES 1600000
#define IN_F 256
#define H1_F 128
#define H2_F 64
#define OUT_F 2
#define BN_EPS 1e-5f

#define NBUK 782          // ceil(50000/64) buckets of 64 nodes
#define BCAP 3584         // LDS edge capacity per bucket in build (avg 2048)
#define CHUNK 8192        // edges per chunk in the two-level counting sort
#define NCHUNK 196        // ceil(1600000/8192)
#define FC 32             // features per aggregation chunk (slice = N*32*2B = 3.2MB < 4MiB L2)

typedef __attribute__((ext_vector_type(8))) short bf16x8;   // 8 bf16 in 4 VGPRs
typedef __attribute__((ext_vector_type(4))) float f32x4;
typedef __attribute__((ext_vector_type(4))) int   i32x4;    // ext-vector (nontemporal-compatible)
typedef __attribute__((ext_vector_type(2))) unsigned u32x2;

// ---------------------------------------------------------------- bf16 helpers
__device__ __forceinline__ unsigned short f2b(float f) {
    union { float f; unsigned u; } v; v.f = f;
    unsigned r = (v.u + 0x7FFFu + ((v.u >> 16) & 1u)) >> 16;
    return (unsigned short)r;
}
__device__ __forceinline__ float b2f(unsigned short b) {
    union { unsigned u; float f; } v; v.u = ((unsigned)b) << 16;
    return v.f;
}
__device__ __forceinline__ void add2(float& a0, float& a1, unsigned u) {
    union { unsigned u; float f; } lo, hi;
    lo.u = u << 16;
    hi.u = u & 0xFFFF0000u;
    a0 += lo.f; a1 += hi.f;
}

// ---------------------------------------------------------------- pass A: per-chunk bucket histogram
//   h is bucket-major: h[bucket][chunk]; tot[bucket] accumulated via fire-and-forget atomics
__launch_bounds__(512)
__global__ void chist_kernel(const int* __restrict__ dst, int* __restrict__ h,
                             int* __restrict__ tot) {
    __shared__ int lh[NBUK];
    const int c = blockIdx.x;
    for (int i = threadIdx.x; i < NBUK; i += 512) lh[i] = 0;
    __syncthreads();
    const int e0 = c * CHUNK;
    const int e1 = min(e0 + CHUNK, N_EDGES);
    const i32x4* p = (const i32x4*)(dst + e0);
    const int n4 = (e1 - e0) >> 2;
    for (int i = threadIdx.x; i < n4; i += 512) {
        i32x4 d = __builtin_nontemporal_load(p + i);
        atomicAdd(&lh[d.x >> 6], 1);
        atomicAdd(&lh[d.y >> 6], 1);
        atomicAdd(&lh[d.z >> 6], 1);
        atomicAdd(&lh[d.w >> 6], 1);
    }
    __syncthreads();
    for (int i = threadIdx.x; i < NBUK; i += 512) {
        int v = lh[i];
        h[(size_t)i * NCHUNK + c] = v;          // bucket-major
        if (v) atomicAdd(&tot[i], v);           // fire-and-forget
    }
}

// ---------------------------------------------------------------- pass B1: scan 782 bucket totals (1 block, tiny)
__global__ void bscan_kernel(const int* __restrict__ tot, int* __restrict__ boff,
                             int* __restrict__ rowptr) {
    __shared__ int tmp[1024];
    const int t = threadIdx.x;
    int v = (t < NBUK) ? tot[t] : 0;
    tmp[t] = v;
    __syncthreads();
    for (int off = 1; off < 1024; off <<= 1) {
        int a = (t >= off) ? tmp[t - off] : 0;
        __syncthreads();
        tmp[t] += a;
        __syncthreads();
    }
    if (t < NBUK) boff[t] = tmp[t] - v;   // exclusive
    if (t == 0) { boff[NBUK] = N_EDGES; rowptr[N_NODES] = N_EDGES; }
}

// ---------------------------------------------------------------- pass B2: rewrite h rows as exact (chunk) start offsets (parallel over buckets)
__global__ void boffs_kernel(int* __restrict__ h, const int* __restrict__ boff) {
    const int t = blockIdx.x * blockDim.x + threadIdx.x;
    if (t >= NBUK) return;
    int run = boff[t];
    int* row = h + (size_t)t * NCHUNK;
    for (int c = 0; c < NCHUNK; ++c) {
        int v = row[c];
        row[c] = run;
        run += v;
    }
}

// ---------------------------------------------------------------- pass C: scatter to precomputed slots (LDS cursors only)
__launch_bounds__(512)
__global__ void cscatter_kernel(const int* __restrict__ src, const int* __restrict__ dst,
                                const int* __restrict__ h, unsigned* __restrict__ bedges) {
    __shared__ int cur[NBUK];
    const int c = blockIdx.x;
    for (int i = threadIdx.x; i < NBUK; i += 512) cur[i] = h[(size_t)i * NCHUNK + c];
    __syncthreads();
    const int e0 = c * CHUNK;
    const int e1 = min(e0 + CHUNK, N_EDGES);
    const i32x4* pd = (const i32x4*)(dst + e0);
    const i32x4* ps = (const i32x4*)(src + e0);
    const int n4 = (e1 - e0) >> 2;
    for (int i = threadIdx.x; i < n4; i += 512) {
        i32x4 d = __builtin_nontemporal_load(pd + i);
        i32x4 s = __builtin_nontemporal_load(ps + i);
        int slot;
        slot = atomicAdd(&cur[d.x >> 6], 1); bedges[slot] = (unsigned)s.x | ((unsigned)d.x << 16);
        slot = atomicAdd(&cur[d.y >> 6], 1); bedges[slot] = (unsigned)s.y | ((unsigned)d.y << 16);
        slot = atomicAdd(&cur[d.z >> 6], 1); bedges[slot] = (unsigned)s.z | ((unsigned)d.z << 16);
        slot = atomicAdd(&cur[d.w >> 6], 1); bedges[slot] = (unsigned)s.w | ((unsigned)d.w << 16);
    }
}

// ---------------------------------------------------------------- per-bucket CSR build
__launch_bounds__(256)
__global__ void build_kernel(const unsigned* __restrict__ bedges, const int* __restrict__ boff,
                             unsigned short* __restrict__ perm, int* __restrict__ rowptr,
                             float* __restrict__ dinv) {
    __shared__ unsigned e_lds[BCAP];
    __shared__ unsigned short p_lds[BCAP];
    __shared__ int ncnt[64], ncur[64];

    const int b = blockIdx.x;
    const int t = threadIdx.x;
    const int start = boff[b];
    const int end   = boff[b + 1];
    const int cnt   = end - start;
    const bool fits = (cnt <= BCAP);

    if (t < 64) ncnt[t] = 0;
    __syncthreads();

    for (int i = t; i < cnt; i += 256) {
        unsigned e = bedges[start + i];
        if (fits) e_lds[i] = e;
        atomicAdd(&ncnt[(e >> 16) & 63], 1);
    }
    __syncthreads();

    if (t == 0) {
        int a = 0;
        for (int i = 0; i < 64; ++i) { ncur[i] = a; a += ncnt[i]; }
    }
    __syncthreads();

    if (t < 64) {
        int node = b * 64 + t;
        if (node < N_NODES) {
            rowptr[node] = start + ncur[t];
            dinv[node]   = rsqrtf((float)ncnt[t] + 1.0f);   // +1 self loop
        }
    }
    __syncthreads();

    for (int i = t; i < cnt; i += 256) {
        unsigned e = fits ? e_lds[i] : bedges[start + i];
        int slot = atomicAdd(&ncur[(e >> 16) & 63], 1);
        unsigned short s = (unsigned short)(e & 0xFFFFu);
        if (fits) p_lds[slot] = s;
        else      perm[start + slot] = s;
    }
    if (fits) {
        __syncthreads();
        for (int i = t; i < cnt; i += 256) perm[start + i] = p_lds[i];
    }
}

// ---------------------------------------------------------------- weight transpose+convert: WT[n][k] = bf16(W[k][n])
__global__ void wt_kernel(const float* __restrict__ W, unsigned short* __restrict__ WT,
                          int K, int N) {
    int i = blockIdx.x * blockDim.x + threadIdx.x;
    if (i < N * K) {
        int n = i / K, k = i % K;
        WT[i] = f2b(W[(size_t)k * N + n]);
    }
}

// ---------------------------------------------------------------- MFMA GEMM, chunk-major bf16 output
// C layout: [f>>5][r][f&31] (chunk-major, FC=32).  A: row-major fp32, or chunk-major bf16.
template <int KSTEPS, int NTILES, bool A_BF16_CHUNKED>
__launch_bounds__(256)
__global__ void mfma_gemm_kernel(const void* __restrict__ Ap, const unsigned short* __restrict__ BT,
                                 const float* __restrict__ dscale, unsigned short* __restrict__ C,
                                 int M) {
    constexpr int K  = KSTEPS * 32;
    const int wave = threadIdx.x >> 6;
    const int lane = threadIdx.x & 63;
    const int r0   = (blockIdx.x * 4 + wave) * 16;
    const int m    = lane & 15;
    const int kb   = lane >> 4;          // 0..3

    int arow = r0 + m;
    if (arow >= M) arow = M - 1;         // clamp loads; stores guarded

    f32x4 acc[NTILES];
#pragma unroll
    for (int nt = 0; nt < NTILES; ++nt) acc[nt] = (f32x4)(0.f);

#pragma unroll
    for (int ks = 0; ks < KSTEPS; ++ks) {
        const int k0 = ks * 32 + kb * 8;
        bf16x8 a;
        if constexpr (A_BF16_CHUNKED) {
            // chunk-major bf16: [ks][row][32]; kb*8 never crosses the 32-boundary
            a = *(const bf16x8*)((const unsigned short*)Ap +
                                 (size_t)ks * N_NODES * FC + (size_t)arow * FC + kb * 8);
        } else {
            const float* af = (const float*)Ap + (size_t)arow * K + k0;
            f32x4 lo = __builtin_nontemporal_load((const f32x4*)af);
            f32x4 hi = __builtin_nontemporal_load((const f32x4*)(af + 4));
            union { bf16x8 v; unsigned short u[8]; } pk;
            pk.u[0] = f2b(lo.x); pk.u[1] = f2b(lo.y); pk.u[2] = f2b(lo.z); pk.u[3] = f2b(lo.w);
            pk.u[4] = f2b(hi.x); pk.u[5] = f2b(hi.y); pk.u[6] = f2b(hi.z); pk.u[7] = f2b(hi.w);
            a = pk.v;
        }
#pragma unroll
        for (int nt = 0; nt < NTILES; ++nt) {
            bf16x8 b = *(const bf16x8*)(BT + (size_t)(nt * 16 + m) * K + k0);
            acc[nt] = __builtin_amdgcn_mfma_f32_16x16x32_bf16(a, b, acc[nt], 0, 0, 0);
        }
    }

#pragma unroll
    for (int reg = 0; reg < 4; ++reg) {
        const int r = r0 + kb * 4 + reg;
        if (r < M) {
            const float ds = dscale[r];
#pragma unroll
            for (int nt = 0; nt < NTILES; ++nt) {
                // feature f = nt*16 + m -> chunk nt>>1, within-chunk (nt&1)*16 + m
                C[(size_t)(nt >> 1) * N_NODES * FC + (size_t)r * FC + ((nt & 1) << 4) + m] =
                    f2b(acc[nt][reg] * ds);
            }
        }
    }
}

// ---------------------------------------------------------------- chunked aggregation (3.2MB L2-resident slice)
//   blockIdx.y = feature chunk c; wave per node; 8 edge-groups x 8 lanes x 8B (uint2) loads
__launch_bounds__(256)
__global__ void agg_kernel(const int* __restrict__ rowptr, const unsigned short* __restrict__ perm,
                           const unsigned short* __restrict__ xw,   // chunk-major [c][node][FC]
                           const float* __restrict__ dinv,
                           const float* __restrict__ bias, const float* __restrict__ g,
                           const float* __restrict__ be, const float* __restrict__ m,
                           const float* __restrict__ v,
                           unsigned short* __restrict__ out) {     // chunk-major [c][node][FC]
    const int c = blockIdx.y;
    const unsigned short* xc = xw + (size_t)c * N_NODES * FC;
    const int wave = threadIdx.x >> 6;
    const int node = blockIdx.x * 4 + wave;
    if (node >= N_NODES) return;
    const int lane = threadIdx.x & 63;
    const int grp  = lane >> 3;          // 8 edge groups
    const int fl   = (lane & 7) << 2;    // 4 feats per lane within chunk

    float a0 = 0.f, a1 = 0.f, a2 = 0.f, a3 = 0.f;
    if (grp == 0) {
        u32x2 u = *(const u32x2*)(xc + node * FC + fl);
        add2(a0, a1, u.x);
        add2(a2, a3, u.y);               // self term
    }

    const int start = rowptr[node];
    const int end   = rowptr[node + 1];
    for (int base = start; base < end; base += 64) {
        int pidx = base + lane;
        int pv = (int)__builtin_nontemporal_load(perm + (pidx < end ? pidx : end - 1));
        int ne = end - base;
        if (ne > 64) ne = 64;
        if (ne == 64) {
#pragma unroll
            for (int j = 0; j < 64; j += 8) {
                int s = __shfl(pv, j + grp);
                u32x2 u = *(const u32x2*)(xc + s * FC + fl);
                add2(a0, a1, u.x);
                add2(a2, a3, u.y);
            }
        } else {
            for (int j = 0; j < ne; j += 8) {
                int s = __shfl(pv, j + grp);
                if (j + grp < ne) {
                    u32x2 u = *(const u32x2*)(xc + s * FC + fl);
                    add2(a0, a1, u.x);
                    add2(a2, a3, u.y);
                }
            }
        }
    }

    // combine the 8 edge-groups
#pragma unroll
    for (int off = 8; off <= 32; off <<= 1) {
        a0 += __shfl_xor(a0, off);
        a1 += __shfl_xor(a1, off);
        a2 += __shfl_xor(a2, off);
        a3 += __shfl_xor(a3, off);
    }

    if (lane < 8) {
        const float dv = dinv[node];
        const int f = c * FC + fl;
        float s0 = g[f + 0] * rsqrtf(v[f + 0] + BN_EPS);
        float s1 = g[f + 1] * rsqrtf(v[f + 1] + BN_EPS);
        float s2 = g[f + 2] * rsqrtf(v[f + 2] + BN_EPS);
        float s3 = g[f + 3] * rsqrtf(v[f + 3] + BN_EPS);
        float y0 = fmaxf(a0 * dv * s0 + (bias[f + 0] - m[f + 0]) * s0 + be[f + 0], 0.f);
        float y1 = fmaxf(a1 * dv * s1 + (bias[f + 1] - m[f + 1]) * s1 + be[f + 1], 0.f);
        float y2 = fmaxf(a2 * dv * s2 + (bias[f + 2] - m[f + 2]) * s2 + be[f + 2], 0.f);
        float y3 = fmaxf(a3 * dv * s3 + (bias[f + 3] - m[f + 3]) * s3 + be[f + 3], 0.f);
        u32x2 o;
        o.x = (unsigned)f2b(y0) | ((unsigned)f2b(y1) << 16);
        o.y = (unsigned)f2b(y2) | ((unsigned)f2b(y3) << 16);
        __builtin_nontemporal_store(o, (u32x2*)(out + (size_t)c * N_NODES * FC + node * FC + fl));
    }
}

// ---------------------------------------------------------------- final linear 64 -> 2 (reads chunk-major bf16 h2)
__global__ void final_kernel(const unsigned short* __restrict__ h2, const float* __restrict__ Wl,
                             const float* __restrict__ bl, float* __restrict__ out) {
    __shared__ float w[H2_F * OUT_F];
    if (threadIdx.x < H2_F * OUT_F) w[threadIdx.x] = Wl[threadIdx.x];
    __syncthreads();
    const int i = blockIdx.x * blockDim.x + threadIdx.x;
    if (i >= N_NODES) return;
    float p0 = bl[0], p1 = bl[1];
#pragma unroll
    for (int cc = 0; cc < 2; ++cc) {
        const unsigned* p = (const unsigned*)(h2 + (size_t)cc * N_NODES * FC + i * FC);
#pragma unroll
        for (int q = 0; q < 16; ++q) {
            unsigned t = p[q];
            int f = cc * FC + q * 2;
            float y0 = b2f((unsigned short)(t & 0xFFFF));
            float y1 = b2f((unsigned short)(t >> 16));
            p0 += y0 * w[f * 2 + 0] + y1 * w[(f + 1) * 2 + 0];
            p1 += y0 * w[f * 2 + 1] + y1 * w[(f + 1) * 2 + 1];
        }
    }
    out[(size_t)i * 2 + 0] = p0;
    out[(size_t)i * 2 + 1] = p1;
}

// ---------------------------------------------------------------- launcher
extern "C" void kernel_launch(void* const* d_in, const int* in_sizes, int n_in,
                              void* d_out, int out_size, void* d_ws, size_t ws_size,
                              hipStream_t stream) {
    const float* x   = (const float*)d_in[0];
    const int*   ei  = (const int*)d_in[1];
    const float* W1  = (const float*)d_in[2];
    const float* b1  = (const float*)d_in[3];
    const float* g1  = (const float*)d_in[4];
    const float* be1 = (const float*)d_in[5];
    const float* m1  = (const float*)d_in[6];
    const float* v1  = (const float*)d_in[7];
    const float* W2  = (const float*)d_in[8];
    const float* b2  = (const float*)d_in[9];
    const float* g2  = (const float*)d_in[10];
    const float* be2 = (const float*)d_in[11];
    const float* m2  = (const float*)d_in[12];
    const float* v2  = (const float*)d_in[13];
    const float* Wl  = (const float*)d_in[14];
    const float* bl  = (const float*)d_in[15];

    const int* src = ei;            // edge_index[0]
    const int* dst = ei + N_EDGES;  // edge_index[1]

    // workspace layout (4B units; all chunks 16B-aligned)
    int*            h      = (int*)d_ws;                          // NBUK*NCHUNK (bucket-major)
    int*            tot    = h + NBUK * NCHUNK;                   // 1024
    int*            boff   = tot + 1024;                          // 1024
    int*            rowptr = boff + 1024;                         // 50016
    float*          dinv   = (float*)(rowptr + 50016);            // 50016
    unsigned*       bedges = (unsigned*)(dinv + 50016);           // E
    unsigned short* perm   = (unsigned short*)(bedges + N_EDGES); // E ushorts
    unsigned short* xwb    = perm + N_EDGES;                      // N*128 bf16 (chunk-major)
    unsigned short* h1b    = xwb + (size_t)N_NODES * H1_F;        // N*128 bf16 (chunk-major)
    unsigned short* w1t    = h1b + (size_t)N_NODES * H1_F;        // 128*256 bf16
    unsigned short* w2t    = w1t + H1_F * IN_F;                   // 64*128 bf16

    hipMemsetAsync(tot, 0, 1024 * sizeof(int), stream);

    // ---- CSR build (deterministic slots, no global returning atomics) ----
    chist_kernel<<<NCHUNK, 512, 0, stream>>>(dst, h, tot);
    bscan_kernel<<<1, 1024, 0, stream>>>(tot, boff, rowptr);
    boffs_kernel<<<(NBUK + 255) / 256, 256, 0, stream>>>(h, boff);
    cscatter_kernel<<<NCHUNK, 512, 0, stream>>>(src, dst, h, bedges);
    build_kernel<<<NBUK, 256, 0, stream>>>(bedges, boff, perm, rowptr, dinv);

    // ---- weight transpose/convert ----
    wt_kernel<<<(H1_F * IN_F + 255) / 256, 256, 0, stream>>>(W1, w1t, IN_F, H1_F);
    wt_kernel<<<(H2_F * H1_F + 255) / 256, 256, 0, stream>>>(W2, w2t, H1_F, H2_F);

    // ---- layer 1 ----
    mfma_gemm_kernel<IN_F / 32, H1_F / 16, false><<<(N_NODES + 63) / 64, 256, 0, stream>>>(
        x, w1t, dinv, xwb, N_NODES);
    agg_kernel<<<dim3((N_NODES + 3) / 4, H1_F / FC), 256, 0, stream>>>(
        rowptr, perm, xwb, dinv, b1, g1, be1, m1, v1, h1b);

    // ---- layer 2 ----
    mfma_gemm_kernel<H1_F / 32, H2_F / 16, true><<<(N_NODES + 63) / 64, 256, 0, stream>>>(
        h1b, w2t, dinv, xwb, N_NODES);
    agg_kernel<<<dim3((N_NODES + 3) / 4, H2_F / FC), 256, 0, stream>>>(
        rowptr, perm, xwb, dinv, b2, g2, be2, m2, v2, h1b);

    // ---- final linear ----
    final_kernel<<<(N_NODES + 255) / 256, 256, 0, stream>>>(h1b, Wl, bl, (float*)d_out);
}

// Round 10
// 275.768 us; speedup vs baseline: 1.2064x; 1.1664x over previous
//
#include <hip/hip_runtime.h>

#define N_NODES 50000
#define N_EDGES 1600000
#define IN_F 256
#define H1_F 128
#define H2_F 64
#define OUT_F 2
#define BN_EPS 1e-5f

#define NBUK 782          // ceil(50000/64) buckets of 64 nodes
#define BCAP 3584         // LDS edge capacity per bucket in build (avg 2048)
#define CHUNK 8192        // edges per chunk in the two-level counting sort
#define NCHUNK 196        // ceil(1600000/8192)

typedef __attribute__((ext_vector_type(8))) short bf16x8;   // 8 bf16 in 4 VGPRs
typedef __attribute__((ext_vector_type(4))) float f32x4;
typedef __attribute__((ext_vector_type(4))) int   i32x4;
typedef __attribute__((ext_vector_type(4))) unsigned u32x4;

// ---------------------------------------------------------------- bf16 helpers
__device__ __forceinline__ unsigned short f2b(float f) {
    union { float f; unsigned u; } v; v.f = f;
    unsigned r = (v.u + 0x7FFFu + ((v.u >> 16) & 1u)) >> 16;
    return (unsigned short)r;
}
__device__ __forceinline__ float b2f(unsigned short b) {
    union { unsigned u; float f; } v; v.u = ((unsigned)b) << 16;
    return v.f;
}
__device__ __forceinline__ void add2(float& a0, float& a1, unsigned u) {
    union { unsigned u; float f; } lo, hi;
    lo.u = u << 16;
    hi.u = u & 0xFFFF0000u;
    a0 += lo.f; a1 += hi.f;
}

// ---------------------------------------------------------------- pass A: per-chunk bucket histogram (bucket-major h)
__launch_bounds__(512)
__global__ void chist_kernel(const int* __restrict__ dst, int* __restrict__ h,
                             int* __restrict__ tot) {
    __shared__ int lh[NBUK];
    const int c = blockIdx.x;
    for (int i = threadIdx.x; i < NBUK; i += 512) lh[i] = 0;
    __syncthreads();
    const int e0 = c * CHUNK;
    const int e1 = min(e0 + CHUNK, N_EDGES);
    const i32x4* p = (const i32x4*)(dst + e0);
    const int n4 = (e1 - e0) >> 2;
    for (int i = threadIdx.x; i < n4; i += 512) {
        i32x4 d = __builtin_nontemporal_load(p + i);
        atomicAdd(&lh[d.x >> 6], 1);
        atomicAdd(&lh[d.y >> 6], 1);
        atomicAdd(&lh[d.z >> 6], 1);
        atomicAdd(&lh[d.w >> 6], 1);
    }
    __syncthreads();
    for (int i = threadIdx.x; i < NBUK; i += 512) {
        int v = lh[i];
        h[(size_t)i * NCHUNK + c] = v;
        if (v) atomicAdd(&tot[i], v);
    }
}

// ---------------------------------------------------------------- pass B1: scan bucket totals
__global__ void bscan_kernel(const int* __restrict__ tot, int* __restrict__ boff,
                             int* __restrict__ rowptr) {
    __shared__ int tmp[1024];
    const int t = threadIdx.x;
    int v = (t < NBUK) ? tot[t] : 0;
    tmp[t] = v;
    __syncthreads();
    for (int off = 1; off < 1024; off <<= 1) {
        int a = (t >= off) ? tmp[t - off] : 0;
        __syncthreads();
        tmp[t] += a;
        __syncthreads();
    }
    if (t < NBUK) boff[t] = tmp[t] - v;
    if (t == 0) { boff[NBUK] = N_EDGES; rowptr[N_NODES] = N_EDGES; }
}

// ---------------------------------------------------------------- pass B2: per-bucket run offsets (parallel)
__global__ void boffs_kernel(int* __restrict__ h, const int* __restrict__ boff) {
    const int t = blockIdx.x * blockDim.x + threadIdx.x;
    if (t >= NBUK) return;
    int run = boff[t];
    int* row = h + (size_t)t * NCHUNK;
    for (int c = 0; c < NCHUNK; ++c) {
        int v = row[c];
        row[c] = run;
        run += v;
    }
}

// ---------------------------------------------------------------- pass C: scatter to precomputed slots
__launch_bounds__(512)
__global__ void cscatter_kernel(const int* __restrict__ src, const int* __restrict__ dst,
                                const int* __restrict__ h, unsigned* __restrict__ bedges) {
    __shared__ int cur[NBUK];
    const int c = blockIdx.x;
    for (int i = threadIdx.x; i < NBUK; i += 512) cur[i] = h[(size_t)i * NCHUNK + c];
    __syncthreads();
    const int e0 = c * CHUNK;
    const int e1 = min(e0 + CHUNK, N_EDGES);
    const i32x4* pd = (const i32x4*)(dst + e0);
    const i32x4* ps = (const i32x4*)(src + e0);
    const int n4 = (e1 - e0) >> 2;
    for (int i = threadIdx.x; i < n4; i += 512) {
        i32x4 d = __builtin_nontemporal_load(pd + i);
        i32x4 s = __builtin_nontemporal_load(ps + i);
        int slot;
        slot = atomicAdd(&cur[d.x >> 6], 1); bedges[slot] = (unsigned)s.x | ((unsigned)d.x << 16);
        slot = atomicAdd(&cur[d.y >> 6], 1); bedges[slot] = (unsigned)s.y | ((unsigned)d.y << 16);
        slot = atomicAdd(&cur[d.z >> 6], 1); bedges[slot] = (unsigned)s.z | ((unsigned)d.z << 16);
        slot = atomicAdd(&cur[d.w >> 6], 1); bedges[slot] = (unsigned)s.w | ((unsigned)d.w << 16);
    }
}

// ---------------------------------------------------------------- per-bucket CSR build
__launch_bounds__(256)
__global__ void build_kernel(const unsigned* __restrict__ bedges, const int* __restrict__ boff,
                             unsigned short* __restrict__ perm, int* __restrict__ rowptr,
                             float* __restrict__ dinv) {
    __shared__ unsigned e_lds[BCAP];
    __shared__ unsigned short p_lds[BCAP];
    __shared__ int ncnt[64], ncur[64];

    const int b = blockIdx.x;
    const int t = threadIdx.x;
    const int start = boff[b];
    const int end   = boff[b + 1];
    const int cnt   = end - start;
    const bool fits = (cnt <= BCAP);

    if (t < 64) ncnt[t] = 0;
    __syncthreads();

    for (int i = t; i < cnt; i += 256) {
        unsigned e = bedges[start + i];
        if (fits) e_lds[i] = e;
        atomicAdd(&ncnt[(e >> 16) & 63], 1);
    }
    __syncthreads();

    if (t == 0) {
        int a = 0;
        for (int i = 0; i < 64; ++i) { ncur[i] = a; a += ncnt[i]; }
    }
    __syncthreads();

    if (t < 64) {
        int node = b * 64 + t;
        if (node < N_NODES) {
            rowptr[node] = start + ncur[t];
            dinv[node]   = rsqrtf((float)ncnt[t] + 1.0f);   // +1 self loop
        }
    }
    __syncthreads();

    for (int i = t; i < cnt; i += 256) {
        unsigned e = fits ? e_lds[i] : bedges[start + i];
        int slot = atomicAdd(&ncur[(e >> 16) & 63], 1);
        unsigned short s = (unsigned short)(e & 0xFFFFu);
        if (fits) p_lds[slot] = s;
        else      perm[start + slot] = s;
    }
    if (fits) {
        __syncthreads();
        for (int i = t; i < cnt; i += 256) perm[start + i] = p_lds[i];
    }
}

// ---------------------------------------------------------------- weight transpose+convert: WT[n][k] = bf16(W[k][n])
__global__ void wt_kernel(const float* __restrict__ W, unsigned short* __restrict__ WT,
                          int K, int N) {
    int i = blockIdx.x * blockDim.x + threadIdx.x;
    if (i < N * K) {
        int n = i / K, k = i % K;
        WT[i] = f2b(W[(size_t)k * N + n]);
    }
}

// ---------------------------------------------------------------- BN fold: sc = g*rsqrt(v+eps), sh = (b-m)*sc + be
__global__ void bnprep_kernel(const float* __restrict__ g, const float* __restrict__ be,
                              const float* __restrict__ m, const float* __restrict__ v,
                              const float* __restrict__ bias, float* __restrict__ sc,
                              float* __restrict__ sh, int F) {
    int f = blockIdx.x * blockDim.x + threadIdx.x;
    if (f < F) {
        float s = g[f] * rsqrtf(v[f] + BN_EPS);
        sc[f] = s;
        sh[f] = (bias[f] - m[f]) * s + be[f];
    }
}

// ---------------------------------------------------------------- MFMA GEMM, row-major bf16 output
template <int KSTEPS, int NTILES, bool A_BF16>
__launch_bounds__(256)
__global__ void mfma_gemm_kernel(const void* __restrict__ Ap, const unsigned short* __restrict__ BT,
                                 const float* __restrict__ dscale, unsigned short* __restrict__ C,
                                 int M) {
    constexpr int K  = KSTEPS * 32;
    constexpr int NF = NTILES * 16;
    const int wave = threadIdx.x >> 6;
    const int lane = threadIdx.x & 63;
    const int r0   = (blockIdx.x * 4 + wave) * 16;
    const int m    = lane & 15;
    const int kb   = lane >> 4;

    int arow = r0 + m;
    if (arow >= M) arow = M - 1;

    f32x4 acc[NTILES];
#pragma unroll
    for (int nt = 0; nt < NTILES; ++nt) acc[nt] = (f32x4)(0.f);

#pragma unroll
    for (int ks = 0; ks < KSTEPS; ++ks) {
        const int k0 = ks * 32 + kb * 8;
        bf16x8 a;
        if constexpr (A_BF16) {
            a = *(const bf16x8*)((const unsigned short*)Ap + (size_t)arow * K + k0);
        } else {
            const float* af = (const float*)Ap + (size_t)arow * K + k0;
            f32x4 lo = __builtin_nontemporal_load((const f32x4*)af);
            f32x4 hi = __builtin_nontemporal_load((const f32x4*)(af + 4));
            union { bf16x8 v; unsigned short u[8]; } pk;
            pk.u[0] = f2b(lo.x); pk.u[1] = f2b(lo.y); pk.u[2] = f2b(lo.z); pk.u[3] = f2b(lo.w);
            pk.u[4] = f2b(hi.x); pk.u[5] = f2b(hi.y); pk.u[6] = f2b(hi.z); pk.u[7] = f2b(hi.w);
            a = pk.v;
        }
#pragma unroll
        for (int nt = 0; nt < NTILES; ++nt) {
            bf16x8 b = *(const bf16x8*)(BT + (size_t)(nt * 16 + m) * K + k0);
            acc[nt] = __builtin_amdgcn_mfma_f32_16x16x32_bf16(a, b, acc[nt], 0, 0, 0);
        }
    }

#pragma unroll
    for (int reg = 0; reg < 4; ++reg) {
        const int r = r0 + kb * 4 + reg;
        if (r < M) {
            const float ds = dscale[r];
#pragma unroll
            for (int nt = 0; nt < NTILES; ++nt)
                C[(size_t)r * NF + nt * 16 + m] = f2b(acc[nt][reg] * ds);
        }
    }
}

// ---------------------------------------------------------------- fused aggregation, row-major, deep MLP
//   one wave per node; LPE=HF/8 lanes per edge (16B bf16x8 each); G=64/LPE edges in flight; unroll x2
template <int HF, bool FINAL>
__launch_bounds__(256)
__global__ void agg_kernel(const int* __restrict__ rowptr, const unsigned short* __restrict__ perm,
                           const unsigned short* __restrict__ xw, const float* __restrict__ dinv,
                           const float* __restrict__ sc, const float* __restrict__ sh,
                           const float* __restrict__ Wl, const float* __restrict__ bl,
                           void* __restrict__ outp) {
    constexpr int LPE = HF / 8;    // lanes per edge (16 for 128, 8 for 64)
    constexpr int G   = 64 / LPE;  // edge groups in flight (4 or 8)
    const int wave = threadIdx.x >> 6;
    const int node = blockIdx.x * 4 + wave;
    if (node >= N_NODES) return;
    const int lane = threadIdx.x & 63;
    const int grp  = lane / LPE;
    const int fl   = (lane % LPE) * 8;   // 8 feats per lane

    float aA[8], aB[8];
#pragma unroll
    for (int i = 0; i < 8; ++i) { aA[i] = 0.f; aB[i] = 0.f; }

    // self term (group 0 only)
    if (grp == 0) {
        u32x4 u = *(const u32x4*)(xw + (size_t)node * HF + fl);
#pragma unroll
        for (int i = 0; i < 4; ++i) add2(aA[2 * i], aA[2 * i + 1], u[i]);
    }

    const int start = rowptr[node];
    const int end   = rowptr[node + 1];
    for (int base = start; base < end; base += 64) {
        int pidx = base + lane;
        int pv = (int)__builtin_nontemporal_load(perm + (pidx < end ? pidx : end - 1));
        int ne = end - base;
        if (ne > 64) ne = 64;
        if (ne == 64) {
#pragma unroll
            for (int j = 0; j < 64; j += 2 * G) {
                int s0 = __shfl(pv, j + grp);
                int s1 = __shfl(pv, j + G + grp);
                u32x4 u0 = *(const u32x4*)(xw + (size_t)s0 * HF + fl);
                u32x4 u1 = *(const u32x4*)(xw + (size_t)s1 * HF + fl);
#pragma unroll
                for (int i = 0; i < 4; ++i) add2(aA[2 * i], aA[2 * i + 1], u0[i]);
#pragma unroll
                for (int i = 0; i < 4; ++i) add2(aB[2 * i], aB[2 * i + 1], u1[i]);
            }
        } else {
            for (int j = 0; j < ne; j += G) {
                int s = __shfl(pv, j + grp);
                if (j + grp < ne) {
                    u32x4 u = *(const u32x4*)(xw + (size_t)s * HF + fl);
#pragma unroll
                    for (int i = 0; i < 4; ++i) add2(aA[2 * i], aA[2 * i + 1], u[i]);
                }
            }
        }
    }

#pragma unroll
    for (int i = 0; i < 8; ++i) aA[i] += aB[i];

    // reduce across edge groups (lanes LPE apart hold same feature slice)
#pragma unroll
    for (int off = LPE; off < 64; off <<= 1)
#pragma unroll
        for (int i = 0; i < 8; ++i) aA[i] += __shfl_xor(aA[i], off);

    const float dv = dinv[node];
    f32x4 scl = *(const f32x4*)(sc + fl);
    f32x4 sch = *(const f32x4*)(sc + fl + 4);
    f32x4 shl = *(const f32x4*)(sh + fl);
    f32x4 shh = *(const f32x4*)(sh + fl + 4);
    float y[8];
#pragma unroll
    for (int i = 0; i < 4; ++i) {
        y[i]     = fmaxf(aA[i] * (dv * scl[i]) + shl[i], 0.f);
        y[i + 4] = fmaxf(aA[i + 4] * (dv * sch[i]) + shh[i], 0.f);
    }

    if constexpr (!FINAL) {
        if (lane < LPE) {
            u32x4 o;
#pragma unroll
            for (int i = 0; i < 4; ++i)
                o[i] = (unsigned)f2b(y[2 * i]) | ((unsigned)f2b(y[2 * i + 1]) << 16);
            __builtin_nontemporal_store(o, (u32x4*)((unsigned short*)outp + (size_t)node * HF + fl));
        }
    } else {
        // fused 64->2 linear: every lane holds feats fl..fl+7 (duplicated across groups)
        float p0 = 0.f, p1 = 0.f;
#pragma unroll
        for (int i = 0; i < 8; ++i) {
            float w0 = Wl[(fl + i) * 2 + 0];
            float w1 = Wl[(fl + i) * 2 + 1];
            p0 += y[i] * w0;
            p1 += y[i] * w1;
        }
        // sum the LPE distinct feature slices (lanes 0..LPE-1)
#pragma unroll
        for (int off = 1; off < LPE; off <<= 1) {
            p0 += __shfl_xor(p0, off);
            p1 += __shfl_xor(p1, off);
        }
        if (lane == 0) {
            float* o = (float*)outp;
            o[(size_t)node * 2 + 0] = p0 + bl[0];
            o[(size_t)node * 2 + 1] = p1 + bl[1];
        }
    }
}

// ---------------------------------------------------------------- launcher
extern "C" void kernel_launch(void* const* d_in, const int* in_sizes, int n_in,
                              void* d_out, int out_size, void* d_ws, size_t ws_size,
                              hipStream_t stream) {
    const float* x   = (const float*)d_in[0];
    const int*   ei  = (const int*)d_in[1];
    const float* W1  = (const float*)d_in[2];
    const float* b1  = (const float*)d_in[3];
    const float* g1  = (const float*)d_in[4];
    const float* be1 = (const float*)d_in[5];
    const float* m1  = (const float*)d_in[6];
    const float* v1  = (const float*)d_in[7];
    const float* W2  = (const float*)d_in[8];
    const float* b2  = (const float*)d_in[9];
    const float* g2  = (const float*)d_in[10];
    const float* be2 = (const float*)d_in[11];
    const float* m2  = (const float*)d_in[12];
    const float* v2  = (const float*)d_in[13];
    const float* Wl  = (const float*)d_in[14];
    const float* bl  = (const float*)d_in[15];

    const int* src = ei;            // edge_index[0]
    const int* dst = ei + N_EDGES;  // edge_index[1]

    // workspace layout (4B units)
    int*            h      = (int*)d_ws;                          // NBUK*NCHUNK (bucket-major)
    int*            tot    = h + NBUK * NCHUNK;                   // 1024
    int*            boff   = tot + 1024;                          // 1024
    int*            rowptr = boff + 1024;                         // 50016
    float*          dinv   = (float*)(rowptr + 50016);            // 50016
    float*          sc1    = dinv + 50016;                        // 128
    float*          sh1    = sc1 + 128;                           // 128
    float*          sc2    = sh1 + 128;                           // 64
    float*          sh2    = sc2 + 64;                            // 64
    unsigned*       bedges = (unsigned*)(sh2 + 64);               // E
    unsigned short* perm   = (unsigned short*)(bedges + N_EDGES); // E ushorts
    unsigned short* xwb    = perm + N_EDGES;                      // N*128 bf16 (row-major)
    unsigned short* h1b    = xwb + (size_t)N_NODES * H1_F;        // N*128 bf16 (row-major)
    unsigned short* w1t    = h1b + (size_t)N_NODES * H1_F;        // 128*256 bf16
    unsigned short* w2t    = w1t + H1_F * IN_F;                   // 64*128 bf16

    hipMemsetAsync(tot, 0, 1024 * sizeof(int), stream);

    // ---- CSR build ----
    chist_kernel<<<NCHUNK, 512, 0, stream>>>(dst, h, tot);
    bscan_kernel<<<1, 1024, 0, stream>>>(tot, boff, rowptr);
    boffs_kernel<<<(NBUK + 255) / 256, 256, 0, stream>>>(h, boff);
    cscatter_kernel<<<NCHUNK, 512, 0, stream>>>(src, dst, h, bedges);
    build_kernel<<<NBUK, 256, 0, stream>>>(bedges, boff, perm, rowptr, dinv);

    // ---- weight / BN prep ----
    wt_kernel<<<(H1_F * IN_F + 255) / 256, 256, 0, stream>>>(W1, w1t, IN_F, H1_F);
    wt_kernel<<<(H2_F * H1_F + 255) / 256, 256, 0, stream>>>(W2, w2t, H1_F, H2_F);
    bnprep_kernel<<<1, 128, 0, stream>>>(g1, be1, m1, v1, b1, sc1, sh1, H1_F);
    bnprep_kernel<<<1, 64, 0, stream>>>(g2, be2, m2, v2, b2, sc2, sh2, H2_F);

    // ---- layer 1 ----
    mfma_gemm_kernel<IN_F / 32, H1_F / 16, false><<<(N_NODES + 63) / 64, 256, 0, stream>>>(
        x, w1t, dinv, xwb, N_NODES);
    agg_kernel<H1_F, false><<<(N_NODES + 3) / 4, 256, 0, stream>>>(
        rowptr, perm, xwb, dinv, sc1, sh1, nullptr, nullptr, h1b);

    // ---- layer 2 + fused final linear ----
    mfma_gemm_kernel<H1_F / 32, H2_F / 16, true><<<(N_NODES + 63) / 64, 256, 0, stream>>>(
        h1b, w2t, dinv, xwb, N_NODES);
    agg_kernel<H2_F, true><<<(N_NODES + 3) / 4, 256, 0, stream>>>(
        rowptr, perm, xwb, dinv, sc2, sh2, Wl, bl, (float*)d_out);
}

// Round 11
// 270.269 us; speedup vs baseline: 1.2310x; 1.0203x over previous
//
#include <hip/hip_runtime.h>

#define N_NODES 50000
#define N_EDGES 1600000
#define IN_F 256
#define H1_F 128
#define H2_F 64
#define OUT_F 2
#define BN_EPS 1e-5f

#define NBUK 782          // ceil(50000/64) buckets of 64 nodes
#define BCAP 3584         // LDS edge capacity per bucket in build (avg 2048)
#define CHUNK 2048        // edges per chunk (782 chunks -> ~3 blocks/CU parallelism)
#define NCHUNK 782        // ceil(1600000/2048) = 782 (exact: 781.25 -> 782)

typedef __attribute__((ext_vector_type(8))) short bf16x8;   // 8 bf16 in 4 VGPRs
typedef __attribute__((ext_vector_type(4))) float f32x4;
typedef __attribute__((ext_vector_type(4))) int   i32x4;
typedef __attribute__((ext_vector_type(4))) unsigned u32x4;

// ---------------------------------------------------------------- bf16 helpers
__device__ __forceinline__ unsigned short f2b(float f) {
    union { float f; unsigned u; } v; v.f = f;
    unsigned r = (v.u + 0x7FFFu + ((v.u >> 16) & 1u)) >> 16;
    return (unsigned short)r;
}
__device__ __forceinline__ float b2f(unsigned short b) {
    union { unsigned u; float f; } v; v.u = ((unsigned)b) << 16;
    return v.f;
}
__device__ __forceinline__ void add2(float& a0, float& a1, unsigned u) {
    union { unsigned u; float f; } lo, hi;
    lo.u = u << 16;
    hi.u = u & 0xFFFF0000u;
    a0 += lo.f; a1 += hi.f;
}

// ---------------------------------------------------------------- pass A: per-chunk bucket histogram (bucket-major h)
__launch_bounds__(256)
__global__ void chist_kernel(const int* __restrict__ dst, int* __restrict__ h,
                             int* __restrict__ tot) {
    __shared__ int lh[NBUK];
    const int c = blockIdx.x;
    for (int i = threadIdx.x; i < NBUK; i += 256) lh[i] = 0;
    __syncthreads();
    const int e0 = c * CHUNK;
    const int e1 = min(e0 + CHUNK, N_EDGES);
    const i32x4* p = (const i32x4*)(dst + e0);
    const int n4 = (e1 - e0) >> 2;
    for (int i = threadIdx.x; i < n4; i += 256) {
        i32x4 d = __builtin_nontemporal_load(p + i);
        atomicAdd(&lh[d.x >> 6], 1);
        atomicAdd(&lh[d.y >> 6], 1);
        atomicAdd(&lh[d.z >> 6], 1);
        atomicAdd(&lh[d.w >> 6], 1);
    }
    __syncthreads();
    for (int i = threadIdx.x; i < NBUK; i += 256) {
        int v = lh[i];
        h[(size_t)i * NCHUNK + c] = v;
        if (v) atomicAdd(&tot[i], v);      // fire-and-forget
    }
}

// ---------------------------------------------------------------- pass B1: scan 782 bucket totals (1 block)
__global__ void bscan_kernel(const int* __restrict__ tot, int* __restrict__ boff,
                             int* __restrict__ rowptr) {
    __shared__ int tmp[1024];
    const int t = threadIdx.x;
    int v = (t < NBUK) ? tot[t] : 0;
    tmp[t] = v;
    __syncthreads();
    for (int off = 1; off < 1024; off <<= 1) {
        int a = (t >= off) ? tmp[t - off] : 0;
        __syncthreads();
        tmp[t] += a;
        __syncthreads();
    }
    if (t < NBUK) boff[t] = tmp[t] - v;
    if (t == 0) { boff[NBUK] = N_EDGES; rowptr[N_NODES] = N_EDGES; }
}

// ---------------------------------------------------------------- pass B2: per-bucket run offsets — one WAVE per bucket (wave-scan)
__launch_bounds__(256)
__global__ void boffs_kernel(int* __restrict__ h, const int* __restrict__ boff) {
    const int b = (blockIdx.x * blockDim.x + threadIdx.x) >> 6;   // wave id = bucket
    if (b >= NBUK) return;
    const int lane = threadIdx.x & 63;
    int run = boff[b];
    int* row = h + (size_t)b * NCHUNK;
    for (int c0 = 0; c0 < NCHUNK; c0 += 64) {
        int idx = c0 + lane;
        int v = (idx < NCHUNK) ? row[idx] : 0;
        int s = v;                                   // inclusive wave scan
#pragma unroll
        for (int off = 1; off < 64; off <<= 1) {
            int t = __shfl_up(s, off);
            if (lane >= off) s += t;
        }
        if (idx < NCHUNK) row[idx] = run + (s - v);  // exclusive + running base
        run += __shfl(s, 63);                        // add block total
    }
}

// ---------------------------------------------------------------- pass C: scatter to precomputed slots (LDS cursors only)
__launch_bounds__(256)
__global__ void cscatter_kernel(const int* __restrict__ src, const int* __restrict__ dst,
                                const int* __restrict__ h, unsigned* __restrict__ bedges) {
    __shared__ int cur[NBUK];
    const int c = blockIdx.x;
    for (int i = threadIdx.x; i < NBUK; i += 256) cur[i] = h[(size_t)i * NCHUNK + c];
    __syncthreads();
    const int e0 = c * CHUNK;
    const int e1 = min(e0 + CHUNK, N_EDGES);
    const i32x4* pd = (const i32x4*)(dst + e0);
    const i32x4* ps = (const i32x4*)(src + e0);
    const int n4 = (e1 - e0) >> 2;
    for (int i = threadIdx.x; i < n4; i += 256) {
        i32x4 d = __builtin_nontemporal_load(pd + i);
        i32x4 s = __builtin_nontemporal_load(ps + i);
        int slot;
        slot = atomicAdd(&cur[d.x >> 6], 1); bedges[slot] = (unsigned)s.x | ((unsigned)d.x << 16);
        slot = atomicAdd(&cur[d.y >> 6], 1); bedges[slot] = (unsigned)s.y | ((unsigned)d.y << 16);
        slot = atomicAdd(&cur[d.z >> 6], 1); bedges[slot] = (unsigned)s.z | ((unsigned)d.z << 16);
        slot = atomicAdd(&cur[d.w >> 6], 1); bedges[slot] = (unsigned)s.w | ((unsigned)d.w << 16);
    }
}

// ---------------------------------------------------------------- per-bucket CSR build
__launch_bounds__(256)
__global__ void build_kernel(const unsigned* __restrict__ bedges, const int* __restrict__ boff,
                             unsigned short* __restrict__ perm, int* __restrict__ rowptr,
                             float* __restrict__ dinv) {
    __shared__ unsigned e_lds[BCAP];
    __shared__ unsigned short p_lds[BCAP];
    __shared__ int ncnt[64], ncur[64];

    const int b = blockIdx.x;
    const int t = threadIdx.x;
    const int start = boff[b];
    const int end   = boff[b + 1];
    const int cnt   = end - start;
    const bool fits = (cnt <= BCAP);

    if (t < 64) ncnt[t] = 0;
    __syncthreads();

    for (int i = t; i < cnt; i += 256) {
        unsigned e = bedges[start + i];
        if (fits) e_lds[i] = e;
        atomicAdd(&ncnt[(e >> 16) & 63], 1);
    }
    __syncthreads();

    if (t == 0) {
        int a = 0;
        for (int i = 0; i < 64; ++i) { ncur[i] = a; a += ncnt[i]; }
    }
    __syncthreads();

    if (t < 64) {
        int node = b * 64 + t;
        if (node < N_NODES) {
            rowptr[node] = start + ncur[t];
            dinv[node]   = rsqrtf((float)ncnt[t] + 1.0f);   // +1 self loop
        }
    }
    __syncthreads();

    for (int i = t; i < cnt; i += 256) {
        unsigned e = fits ? e_lds[i] : bedges[start + i];
        int slot = atomicAdd(&ncur[(e >> 16) & 63], 1);
        unsigned short s = (unsigned short)(e & 0xFFFFu);
        if (fits) p_lds[slot] = s;
        else      perm[start + slot] = s;
    }
    if (fits) {
        __syncthreads();
        for (int i = t; i < cnt; i += 256) perm[start + i] = p_lds[i];
    }
}

// ---------------------------------------------------------------- weight transpose+convert: WT[n][k] = bf16(W[k][n])
__global__ void wt_kernel(const float* __restrict__ W, unsigned short* __restrict__ WT,
                          int K, int N) {
    int i = blockIdx.x * blockDim.x + threadIdx.x;
    if (i < N * K) {
        int n = i / K, k = i % K;
        WT[i] = f2b(W[(size_t)k * N + n]);
    }
}

// ---------------------------------------------------------------- BN fold: sc = g*rsqrt(v+eps), sh = (b-m)*sc + be
__global__ void bnprep_kernel(const float* __restrict__ g, const float* __restrict__ be,
                              const float* __restrict__ m, const float* __restrict__ v,
                              const float* __restrict__ bias, float* __restrict__ sc,
                              float* __restrict__ sh, int F) {
    int f = blockIdx.x * blockDim.x + threadIdx.x;
    if (f < F) {
        float s = g[f] * rsqrtf(v[f] + BN_EPS);
        sc[f] = s;
        sh[f] = (bias[f] - m[f]) * s + be[f];
    }
}

// ---------------------------------------------------------------- MFMA GEMM, row-major bf16 output
template <int KSTEPS, int NTILES, bool A_BF16>
__launch_bounds__(256)
__global__ void mfma_gemm_kernel(const void* __restrict__ Ap, const unsigned short* __restrict__ BT,
                                 const float* __restrict__ dscale, unsigned short* __restrict__ C,
                                 int M) {
    constexpr int K  = KSTEPS * 32;
    constexpr int NF = NTILES * 16;
    const int wave = threadIdx.x >> 6;
    const int lane = threadIdx.x & 63;
    const int r0   = (blockIdx.x * 4 + wave) * 16;
    const int m    = lane & 15;
    const int kb   = lane >> 4;

    int arow = r0 + m;
    if (arow >= M) arow = M - 1;

    f32x4 acc[NTILES];
#pragma unroll
    for (int nt = 0; nt < NTILES; ++nt) acc[nt] = (f32x4)(0.f);

#pragma unroll
    for (int ks = 0; ks < KSTEPS; ++ks) {
        const int k0 = ks * 32 + kb * 8;
        bf16x8 a;
        if constexpr (A_BF16) {
            a = *(const bf16x8*)((const unsigned short*)Ap + (size_t)arow * K + k0);
        } else {
            const float* af = (const float*)Ap + (size_t)arow * K + k0;
            f32x4 lo = __builtin_nontemporal_load((const f32x4*)af);
            f32x4 hi = __builtin_nontemporal_load((const f32x4*)(af + 4));
            union { bf16x8 v; unsigned short u[8]; } pk;
            pk.u[0] = f2b(lo.x); pk.u[1] = f2b(lo.y); pk.u[2] = f2b(lo.z); pk.u[3] = f2b(lo.w);
            pk.u[4] = f2b(hi.x); pk.u[5] = f2b(hi.y); pk.u[6] = f2b(hi.z); pk.u[7] = f2b(hi.w);
            a = pk.v;
        }
#pragma unroll
        for (int nt = 0; nt < NTILES; ++nt) {
            bf16x8 b = *(const bf16x8*)(BT + (size_t)(nt * 16 + m) * K + k0);
            acc[nt] = __builtin_amdgcn_mfma_f32_16x16x32_bf16(a, b, acc[nt], 0, 0, 0);
        }
    }

#pragma unroll
    for (int reg = 0; reg < 4; ++reg) {
        const int r = r0 + kb * 4 + reg;
        if (r < M) {
            const float ds = dscale[r];
#pragma unroll
            for (int nt = 0; nt < NTILES; ++nt)
                C[(size_t)r * NF + nt * 16 + m] = f2b(acc[nt][reg] * ds);
        }
    }
}

// ---------------------------------------------------------------- fused aggregation, row-major, single acc set (low VGPR)
//   one wave per node; LPE=HF/8 lanes per edge (16B bf16x8 each); G=64/LPE edges in flight
template <int HF, bool FINAL>
__launch_bounds__(256)
__global__ void agg_kernel(const int* __restrict__ rowptr, const unsigned short* __restrict__ perm,
                           const unsigned short* __restrict__ xw, const float* __restrict__ dinv,
                           const float* __restrict__ sc, const float* __restrict__ sh,
                           const float* __restrict__ Wl, const float* __restrict__ bl,
                           void* __restrict__ outp) {
    constexpr int LPE = HF / 8;    // lanes per edge (16 for 128, 8 for 64)
    constexpr int G   = 64 / LPE;  // edge groups in flight (4 or 8)
    const int wave = threadIdx.x >> 6;
    const int node = blockIdx.x * 4 + wave;
    if (node >= N_NODES) return;
    const int lane = threadIdx.x & 63;
    const int grp  = lane / LPE;
    const int fl   = (lane % LPE) * 8;   // 8 feats per lane

    float aA[8];
#pragma unroll
    for (int i = 0; i < 8; ++i) aA[i] = 0.f;

    // self term (group 0 only)
    if (grp == 0) {
        u32x4 u = *(const u32x4*)(xw + (size_t)node * HF + fl);
#pragma unroll
        for (int i = 0; i < 4; ++i) add2(aA[2 * i], aA[2 * i + 1], u[i]);
    }

    const int start = rowptr[node];
    const int end   = rowptr[node + 1];
    for (int base = start; base < end; base += 64) {
        int pidx = base + lane;
        int pv = (int)__builtin_nontemporal_load(perm + (pidx < end ? pidx : end - 1));
        int ne = end - base;
        if (ne > 64) ne = 64;
        if (ne == 64) {
#pragma unroll
            for (int j = 0; j < 64; j += G) {
                int s = __shfl(pv, j + grp);
                u32x4 u = *(const u32x4*)(xw + (size_t)s * HF + fl);
#pragma unroll
                for (int i = 0; i < 4; ++i) add2(aA[2 * i], aA[2 * i + 1], u[i]);
            }
        } else {
            for (int j = 0; j < ne; j += G) {
                int s = __shfl(pv, j + grp);
                if (j + grp < ne) {
                    u32x4 u = *(const u32x4*)(xw + (size_t)s * HF + fl);
#pragma unroll
                    for (int i = 0; i < 4; ++i) add2(aA[2 * i], aA[2 * i + 1], u[i]);
                }
            }
        }
    }

    // reduce across edge groups (lanes LPE apart hold same feature slice)
#pragma unroll
    for (int off = LPE; off < 64; off <<= 1)
#pragma unroll
        for (int i = 0; i < 8; ++i) aA[i] += __shfl_xor(aA[i], off);

    const float dv = dinv[node];
    f32x4 scl = *(const f32x4*)(sc + fl);
    f32x4 sch = *(const f32x4*)(sc + fl + 4);
    f32x4 shl = *(const f32x4*)(sh + fl);
    f32x4 shh = *(const f32x4*)(sh + fl + 4);
    float y[8];
#pragma unroll
    for (int i = 0; i < 4; ++i) {
        y[i]     = fmaxf(aA[i] * (dv * scl[i]) + shl[i], 0.f);
        y[i + 4] = fmaxf(aA[i + 4] * (dv * sch[i]) + shh[i], 0.f);
    }

    if constexpr (!FINAL) {
        if (lane < LPE) {
            u32x4 o;
#pragma unroll
            for (int i = 0; i < 4; ++i)
                o[i] = (unsigned)f2b(y[2 * i]) | ((unsigned)f2b(y[2 * i + 1]) << 16);
            __builtin_nontemporal_store(o, (u32x4*)((unsigned short*)outp + (size_t)node * HF + fl));
        }
    } else {
        // fused 64->2 linear: lanes 0..LPE-1 hold distinct feature slices
        float p0 = 0.f, p1 = 0.f;
#pragma unroll
        for (int i = 0; i < 8; ++i) {
            p0 += y[i] * Wl[(fl + i) * 2 + 0];
            p1 += y[i] * Wl[(fl + i) * 2 + 1];
        }
#pragma unroll
        for (int off = 1; off < LPE; off <<= 1) {
            p0 += __shfl_xor(p0, off);
            p1 += __shfl_xor(p1, off);
        }
        if (lane == 0) {
            float* o = (float*)outp;
            o[(size_t)node * 2 + 0] = p0 + bl[0];
            o[(size_t)node * 2 + 1] = p1 + bl[1];
        }
    }
}

// ---------------------------------------------------------------- launcher
extern "C" void kernel_launch(void* const* d_in, const int* in_sizes, int n_in,
                              void* d_out, int out_size, void* d_ws, size_t ws_size,
                              hipStream_t stream) {
    const float* x   = (const float*)d_in[0];
    const int*   ei  = (const int*)d_in[1];
    const float* W1  = (const float*)d_in[2];
    const float* b1  = (const float*)d_in[3];
    const float* g1  = (const float*)d_in[4];
    const float* be1 = (const float*)d_in[5];
    const float* m1  = (const float*)d_in[6];
    const float* v1  = (const float*)d_in[7];
    const float* W2  = (const float*)d_in[8];
    const float* b2  = (const float*)d_in[9];
    const float* g2  = (const float*)d_in[10];
    const float* be2 = (const float*)d_in[11];
    const float* m2  = (const float*)d_in[12];
    const float* v2  = (const float*)d_in[13];
    const float* Wl  = (const float*)d_in[14];
    const float* bl  = (const float*)d_in[15];

    const int* src = ei;            // edge_index[0]
    const int* dst = ei + N_EDGES;  // edge_index[1]

    // workspace layout (4B units)
    int*            h      = (int*)d_ws;                          // NBUK*NCHUNK (bucket-major) ~2.4MB
    int*            tot    = h + (size_t)NBUK * NCHUNK;           // 1024
    int*            boff   = tot + 1024;                          // 1024
    int*            rowptr = boff + 1024;                         // 50016
    float*          dinv   = (float*)(rowptr + 50016);            // 50016
    float*          sc1    = dinv + 50016;                        // 128
    float*          sh1    = sc1 + 128;                           // 128
    float*          sc2    = sh1 + 128;                           // 64
    float*          sh2    = sc2 + 64;                            // 64
    unsigned*       bedges = (unsigned*)(sh2 + 64);               // E
    unsigned short* perm   = (unsigned short*)(bedges + N_EDGES); // E ushorts
    unsigned short* xwb    = perm + N_EDGES;                      // N*128 bf16 (row-major)
    unsigned short* h1b    = xwb + (size_t)N_NODES * H1_F;        // N*128 bf16 (row-major)
    unsigned short* w1t    = h1b + (size_t)N_NODES * H1_F;        // 128*256 bf16
    unsigned short* w2t    = w1t + H1_F * IN_F;                   // 64*128 bf16

    hipMemsetAsync(tot, 0, 1024 * sizeof(int), stream);

    // ---- CSR build ----
    chist_kernel<<<NCHUNK, 256, 0, stream>>>(dst, h, tot);
    bscan_kernel<<<1, 1024, 0, stream>>>(tot, boff, rowptr);
    boffs_kernel<<<(NBUK * 64 + 255) / 256, 256, 0, stream>>>(h, boff);
    cscatter_kernel<<<NCHUNK, 256, 0, stream>>>(src, dst, h, bedges);
    build_kernel<<<NBUK, 256, 0, stream>>>(bedges, boff, perm, rowptr, dinv);

    // ---- weight / BN prep ----
    wt_kernel<<<(H1_F * IN_F + 255) / 256, 256, 0, stream>>>(W1, w1t, IN_F, H1_F);
    wt_kernel<<<(H2_F * H1_F + 255) / 256, 256, 0, stream>>>(W2, w2t, H1_F, H2_F);
    bnprep_kernel<<<1, 128, 0, stream>>>(g1, be1, m1, v1, b1, sc1, sh1, H1_F);
    bnprep_kernel<<<1, 64, 0, stream>>>(g2, be2, m2, v2, b2, sc2, sh2, H2_F);

    // ---- layer 1 ----
    mfma_gemm_kernel<IN_F / 32, H1_F / 16, false><<<(N_NODES + 63) / 64, 256, 0, stream>>>(
        x, w1t, dinv, xwb, N_NODES);
    agg_kernel<H1_F, false><<<(N_NODES + 3) / 4, 256, 0, stream>>>(
        rowptr, perm, xwb, dinv, sc1, sh1, nullptr, nullptr, h1b);

    // ---- layer 2 + fused final linear ----
    mfma_gemm_kernel<H1_F / 32, H2_F / 16, true><<<(N_NODES + 63) / 64, 256, 0, stream>>>(
        h1b, w2t, dinv, xwb, N_NODES);
    agg_kernel<H2_F, true><<<(N_NODES + 3) / 4, 256, 0, stream>>>(
        rowptr, perm, xwb, dinv, sc2, sh2, Wl, bl, (float*)d_out);
}